// Round 1
// baseline (1217.541 us; speedup 1.0000x reference)
//
#include <hip/hip_runtime.h>
#include <hip/hip_bf16.h>
#include <hip/hip_fp16.h>
#include <math.h>

// Problem constants
constexpr int cB   = 2;
constexpr int cS   = 2048;
constexpr int cD   = 1024;
constexpr int cQH  = 16;
constexpr int cKVH = 4;
constexpr int cDH  = 64;
constexpr int cTOPK = 128;
constexpr int cM   = cB * cS;          // 4096 rows for all GEMMs
constexpr int cNB  = cS / 64;          // 32 j-blocks of 64
constexpr int cLSZ = 384;              // kept-list capacity (128 + tie slack)

// Attention tiling
constexpr int cTI  = 16;               // query rows per workgroup
constexpr int cLDW = cS + 2;           // LDS score row stride (pad: 4*cLDW%32=8)

typedef __attribute__((ext_vector_type(8))) short short8;
typedef __attribute__((ext_vector_type(4))) float floatx4;
typedef _Float16 half8 __attribute__((ext_vector_type(8)));

// fp32 -> bf16 round-to-nearest-even (no NaN inputs in this problem)
__device__ inline ushort f2bf(float f) {
    unsigned u = __float_as_uint(f);
    return (ushort)((u + 0x7FFFu + ((u >> 16) & 1u)) >> 16);
}

// ---------------------------------------------------------------------------
// Cast fp32 -> bf16 (raw ushort), n multiple of 4.
// ---------------------------------------------------------------------------
__global__ void cast_f32_bf16(const float* __restrict__ src,
                              ushort* __restrict__ dst, int n) {
    int i4 = (blockIdx.x * blockDim.x + threadIdx.x) * 4;
    if (i4 >= n) return;
    const float4 v = *(const float4*)(src + i4);
    ushort4 r;
    r.x = f2bf(v.x); r.y = f2bf(v.y); r.z = f2bf(v.z); r.w = f2bf(v.w);
    *(ushort4*)(dst + i4) = r;
}

// ---------------------------------------------------------------------------
// Cast fp32 -> f16 (raw ushort), n multiple of 4.
// ---------------------------------------------------------------------------
__global__ void cast_f32_f16(const float* __restrict__ src,
                             ushort* __restrict__ dst, int n) {
    int i4 = (blockIdx.x * blockDim.x + threadIdx.x) * 4;
    if (i4 >= n) return;
    const float4 v = *(const float4*)(src + i4);
    ushort4 r;
    r.x = __builtin_bit_cast(ushort, (_Float16)v.x);
    r.y = __builtin_bit_cast(ushort, (_Float16)v.y);
    r.z = __builtin_bit_cast(ushort, (_Float16)v.z);
    r.w = __builtin_bit_cast(ushort, (_Float16)v.w);
    *(ushort4*)(dst + i4) = r;
}

// ---------------------------------------------------------------------------
// MFMA bf16 GEMM: C[m][n] = sum_k A[m][k] * W[n][k]  (A @ W^T).
// 128x128 block tile, BK=32, 256 threads = 4 waves (2x2 of 64x64).
// ---------------------------------------------------------------------------
__global__ __launch_bounds__(256) void gemm_bf16_bt(
        const ushort* __restrict__ A, const ushort* __restrict__ W,
        float* __restrict__ C, int M, int N, int K) {
    __shared__ short As[4][128][8];
    __shared__ short Bs[4][128][8];

    const int tid  = threadIdx.x;
    const int lane = tid & 63;
    const int w    = tid >> 6;          // 0..3
    const int wm   = (w & 1) * 64;
    const int wn   = (w >> 1) * 64;
    const int m0   = blockIdx.y * 128;
    const int n0   = blockIdx.x * 128;

    const int quad = lane >> 4;
    const int l16  = lane & 15;

    floatx4 acc[4][4];
    #pragma unroll
    for (int mi = 0; mi < 4; ++mi)
        #pragma unroll
        for (int ni = 0; ni < 4; ++ni)
            acc[mi][ni] = (floatx4){0.f, 0.f, 0.f, 0.f};

    const int sr = tid >> 1;            // staging row 0..127
    const int sh = (tid & 1) * 2;       // k-chunk pair 0 or 2

    for (int k0 = 0; k0 < K; k0 += 32) {
        const ushort* sa = A + (size_t)(m0 + sr) * K + k0 + sh * 8;
        const short8 a0 = *(const short8*)sa;
        const short8 a1 = *(const short8*)(sa + 8);
        const ushort* sw = W + (size_t)(n0 + sr) * K + k0 + sh * 8;
        const short8 b0 = *(const short8*)sw;
        const short8 b1 = *(const short8*)(sw + 8);
        *(short8*)&As[sh][sr][0]     = a0;
        *(short8*)&As[sh + 1][sr][0] = a1;
        *(short8*)&Bs[sh][sr][0]     = b0;
        *(short8*)&Bs[sh + 1][sr][0] = b1;
        __syncthreads();

        short8 af[4], bf[4];
        #pragma unroll
        for (int mi = 0; mi < 4; ++mi)
            af[mi] = *(const short8*)&As[quad][wm + mi * 16 + l16][0];
        #pragma unroll
        for (int ni = 0; ni < 4; ++ni)
            bf[ni] = *(const short8*)&Bs[quad][wn + ni * 16 + l16][0];
        #pragma unroll
        for (int mi = 0; mi < 4; ++mi)
            #pragma unroll
            for (int ni = 0; ni < 4; ++ni)
                acc[mi][ni] = __builtin_amdgcn_mfma_f32_16x16x32_bf16(
                    af[mi], bf[ni], acc[mi][ni], 0, 0, 0);
        __syncthreads();
    }

    // D layout: col = lane&15, row = quad*4 + reg
    #pragma unroll
    for (int mi = 0; mi < 4; ++mi)
        #pragma unroll
        for (int ni = 0; ni < 4; ++ni)
            #pragma unroll
            for (int r = 0; r < 4; ++r) {
                const int row = m0 + wm + mi * 16 + quad * 4 + r;
                const int col = n0 + wn + ni * 16 + l16;
                C[(size_t)row * N + col] = acc[mi][ni][r];
            }
}

// ---------------------------------------------------------------------------
// RoPE + scale + cast to f16, out of place.
// src layout (B*S, H, DH) fp32; dst same layout, f16 bits in ushort.
// ---------------------------------------------------------------------------
__global__ void rope_cast_f16(const float* __restrict__ src,
                              ushort* __restrict__ dst, int H, int total,
                              float scale) {
    int idx = blockIdx.x * blockDim.x + threadIdx.x;
    if (idx >= total) return;
    const int d   = idx & 31;
    const int h   = (idx >> 5) % H;
    const int row = idx / (32 * H);
    const int s   = row % cS;
    const float inv_freq = powf(10000.0f, -(float)d / 32.0f);
    const float ang = (float)s * inv_freq;
    const float c  = cosf(ang);
    const float si = sinf(ang);
    const float* p = src + (size_t)row * H * cDH + (size_t)h * cDH;
    const float x1 = p[d];
    const float x2 = p[d + 32];
    const float r1 = (x1 * c - x2 * si) * scale;
    const float r2 = (x2 * c + x1 * si) * scale;
    ushort* o = dst + (size_t)row * H * cDH + (size_t)h * cDH;
    o[d]      = __builtin_bit_cast(ushort, (_Float16)r1);
    o[d + 32] = __builtin_bit_cast(ushort, (_Float16)r2);
}

// ---------------------------------------------------------------------------
// Order-preserving float <-> uint bit maps (no NaNs here).
// ---------------------------------------------------------------------------
__device__ inline unsigned fmap(float f) {
    unsigned u = __float_as_uint(f);
    return (u & 0x80000000u) ? ~u : (u | 0x80000000u);
}
__device__ inline float funmap(unsigned u) {
    unsigned v = (u & 0x80000000u) ? (u & 0x7FFFFFFFu) : ~u;
    return __uint_as_float(v);
}

// ---------------------------------------------------------------------------
// MFMA tile attention with exact top-k threshold.
//
// Workgroup = 512 threads = 8 waves, owns cTI=16 query rows of one (b,h).
// Phase 1: scores via mfma_f32_16x16x32_f16 (16 q-rows x 16 keys per block,
//   K=64 via 2 chained MFMAs). Fragment layout taken from gemm_bf16_bt above
//   (A/B: row = lane&15, k = quad*8+e; D: row = quad*4+r, col = lane&15).
//   Full f32 score rows stored in LDS (16 x cLDW, pad=2 so the 4 quads'
//   ds_write_b32 spread across banks; 4*cLDW % 32 == 8).
// Phase 2 (per wave, 2 rows sequentially): reload scores into the proven
//   key[32] per-lane register layout (permuted ownership, R11), then the
//   UNCHANGED exact bisection -> compaction -> softmax -> PV path.
// Proven constraints carried over:
//  - key[32] 1D fully unrolled (R5/R6: 2D/runtime-indexed -> scratch spill).
//  - no cross-half (>=32) shuffles on the critical chain (R10).
//  - permuted key ownership (R11): selection is permutation-invariant.
// PV widened to 8 independent accumulator chains (occupancy is now 8 waves/CU
// due to 152KB LDS -> need more MLP per wave).
// Big-it tiles dispatched first (descending it) to avoid a straggler tail.
// ---------------------------------------------------------------------------
__global__ __launch_bounds__(512) void attn_tile_kernel(
        const ushort* __restrict__ qf, const ushort* __restrict__ kf,
        const ushort* __restrict__ vf, ushort* __restrict__ out) {
    extern __shared__ char smem[];
    float*    Sc  = (float*)smem;                                   // [cTI][cLDW]
    unsigned* klA = (unsigned*)(smem + (size_t)cTI * cLDW * sizeof(float));
    int*      jlA = (int*)(klA + 8 * cLSZ);

    const int lane = threadIdx.x & 63;
    const int wv   = __builtin_amdgcn_readfirstlane(threadIdx.x >> 6); // 0..7

    // grid: 32 * 128 blocks; it descending so the biggest tiles start first
    const int x  = blockIdx.x;
    const int it = (cS / cTI - 1) - (x >> 5);   // 127..0
    const int bh = x & 31;
    const int h  = bh & 15;
    const int b  = bh >> 4;
    const int kvh = h >> 2;                     // h / (QH/KVH)
    const int i0  = it * cTI;
    const int nk16 = it + 1;                    // 16-key blocks to compute

    const size_t bS = (size_t)b * cS;
    const int l16   = lane & 15;
    const int quad  = lane >> 4;

    // ---- Phase 1: scores via MFMA, scattered across 8 waves ---------------
    // A-frags: q rows i0 + l16, dims quad*8..quad*8+7 and +32 (f16, pre-scaled)
    const ushort* qp = qf + ((bS + i0 + l16) * cQH + h) * cDH + quad * 8;
    const uint4 a0 = *(const uint4*)qp;
    const uint4 a1 = *(const uint4*)(qp + 32);
    const half8 a0h = __builtin_bit_cast(half8, a0);
    const half8 a1h = __builtin_bit_cast(half8, a1);

    int jb16 = wv;
    if (jb16 < nk16) {
        const ushort* kp0 = kf + ((bS + (jb16 << 4) + l16) * cKVH + kvh) * cDH + quad * 8;
        uint4 pb0 = *(const uint4*)kp0;
        uint4 pb1 = *(const uint4*)(kp0 + 32);
        while (jb16 < nk16) {
            const uint4 b0 = pb0;
            const uint4 b1 = pb1;
            const int jn = jb16 + 8;
            if (jn < nk16) {   // software pipeline: prefetch next key block
                const ushort* kp = kf + ((bS + (jn << 4) + l16) * cKVH + kvh) * cDH + quad * 8;
                pb0 = *(const uint4*)kp;
                pb1 = *(const uint4*)(kp + 32);
            }
            floatx4 acc = (floatx4){0.f, 0.f, 0.f, 0.f};
            acc = __builtin_amdgcn_mfma_f32_16x16x32_f16(
                a0h, __builtin_bit_cast(half8, b0), acc, 0, 0, 0);
            acc = __builtin_amdgcn_mfma_f32_16x16x32_f16(
                a1h, __builtin_bit_cast(half8, b1), acc, 0, 0, 0);
            // D: row = quad*4 + r (q row in tile), col = l16 (key in block)
            const int colbase = (jb16 << 4) + l16;
            #pragma unroll
            for (int r2 = 0; r2 < 4; ++r2)
                Sc[(quad * 4 + r2) * cLDW + colbase] = acc[r2];
            jb16 = jn;
        }
    }
    __syncthreads();

    // ---- Phase 2: per-row exact top-k + softmax + PV (2 rows per wave) ----
    const int g     = lane >> 2;
    const int jperm = ((lane & 3) << 4) + (lane >> 2);   // permuted ownership
    (void)g;
    unsigned* kl = klA + wv * cLSZ;
    int*      jl = jlA + wv * cLSZ;
    const int vbase0 = (int)(((unsigned)bS * cKVH + kvh) * cDH);

    for (int rr = 0; rr < 2; ++rr) {
        const int r  = wv + rr * 8;          // row within tile, 0..15
        const int i  = i0 + r;
        const int nb = (i >> 6) + 1;

        // reload this row's scores into per-lane keys (2-way LDS reads: free)
        unsigned key[cNB];
        #pragma unroll
        for (int jb = 0; jb < cNB; ++jb) {
            unsigned kreg = 0u;
            if (jb < nb) {
                const int j = (jb << 6) + jperm;
                if (j <= i) kreg = fmap(Sc[r * cLDW + j]);
            }
            key[jb] = kreg;
        }

        // row max + min over valid keys (valid keys are never 0)
        unsigned um = 0u, un = 0xFFFFFFFFu;
        #pragma unroll
        for (int jb = 0; jb < cNB; ++jb) {
            if (jb >= nb) break;
            const unsigned kk = key[jb];
            um = max(um, kk);
            un = min(un, kk ? kk : 0xFFFFFFFFu);
        }
        #pragma unroll
        for (int off = 32; off >= 1; off >>= 1) {
            um = max(um, (unsigned)__shfl_xor((int)um, off));
            un = min(un, (unsigned)__shfl_xor((int)un, off));
        }
        const float mrow = funmap(um);

        // exact 128th-largest key via bisection in [un, um]
        unsigned lo = un, hi = um;
        while (lo < hi) {
            const unsigned d   = hi - lo;
            const unsigned mid = lo + (d >> 1) + (d & 1u);
            int cnt2 = 0;
            #pragma unroll
            for (int jb = 0; jb < cNB; ++jb) {
                if (jb >= nb) break;
                cnt2 += __popcll(__ballot(key[jb] >= mid));
            }
            if (cnt2 >= cTOPK) lo = mid; else hi = mid - 1u;
        }
        const unsigned ustar = lo;

        // ballot-prefix compaction of kept (j, key) into LDS
        const unsigned long long mlt = (1ull << lane) - 1ull;
        int base = 0;
        #pragma unroll
        for (int jb = 0; jb < cNB; ++jb) {
            if (jb >= nb) break;
            const int j = (jb << 6) + jperm;
            const bool keep = (j <= i) && (key[jb] >= ustar);
            const unsigned long long mk = __ballot(keep);
            const int pos = base + __popcll(mk & mlt);
            if (keep && pos < cLSZ) {
                kl[pos] = key[jb];
                jl[pos] = vbase0 + j * (cKVH * cDH);   // v element offset
            }
            base += __popcll(mk);
        }
        const int cnt = min(base, cLSZ);

        // weights + Z
        float zp = 0.f;
        for (int t = lane; t < cnt; t += 64) {
            const float s  = funmap(kl[t]);
            const float wt = __expf(s - mrow);
            ((float*)kl)[t] = wt;
            zp += wt;
        }
        #pragma unroll
        for (int off = 32; off >= 1; off >>= 1) zp += __shfl_xor(zp, off);
        const float invZ = 1.0f / zp;

        // PV: lane = d, f16 v, 8 independent accumulator chains
        float ac0 = 0.f, ac1 = 0.f, ac2 = 0.f, ac3 = 0.f;
        float ac4 = 0.f, ac5 = 0.f, ac6 = 0.f, ac7 = 0.f;
        int t = 0;
        for (; t + 7 < cnt; t += 8) {
            const float wt0 = ((float*)kl)[t];
            const float wt1 = ((float*)kl)[t + 1];
            const float wt2 = ((float*)kl)[t + 2];
            const float wt3 = ((float*)kl)[t + 3];
            const float wt4 = ((float*)kl)[t + 4];
            const float wt5 = ((float*)kl)[t + 5];
            const float wt6 = ((float*)kl)[t + 6];
            const float wt7 = ((float*)kl)[t + 7];
            const int vo0 = jl[t];
            const int vo1 = jl[t + 1];
            const int vo2 = jl[t + 2];
            const int vo3 = jl[t + 3];
            const int vo4 = jl[t + 4];
            const int vo5 = jl[t + 5];
            const int vo6 = jl[t + 6];
            const int vo7 = jl[t + 7];
            ac0 += wt0 * (float)__builtin_bit_cast(_Float16, vf[vo0 + lane]);
            ac1 += wt1 * (float)__builtin_bit_cast(_Float16, vf[vo1 + lane]);
            ac2 += wt2 * (float)__builtin_bit_cast(_Float16, vf[vo2 + lane]);
            ac3 += wt3 * (float)__builtin_bit_cast(_Float16, vf[vo3 + lane]);
            ac4 += wt4 * (float)__builtin_bit_cast(_Float16, vf[vo4 + lane]);
            ac5 += wt5 * (float)__builtin_bit_cast(_Float16, vf[vo5 + lane]);
            ac6 += wt6 * (float)__builtin_bit_cast(_Float16, vf[vo6 + lane]);
            ac7 += wt7 * (float)__builtin_bit_cast(_Float16, vf[vo7 + lane]);
        }
        for (; t < cnt; ++t) {
            const float wt = ((float*)kl)[t];
            const int   vo = jl[t];
            ac0 += wt * (float)__builtin_bit_cast(_Float16, vf[vo + lane]);
        }
        const float acc = ((ac0 + ac1) + (ac2 + ac3)) + ((ac4 + ac5) + (ac6 + ac7));
        out[((bS + i) * cQH + h) * cDH + lane] = f2bf(acc * invZ);
    }
}

// ---------------------------------------------------------------------------
// Launch
// ---------------------------------------------------------------------------
extern "C" void kernel_launch(void* const* d_in, const int* in_sizes, int n_in,
                              void* d_out, int out_size, void* d_ws, size_t ws_size,
                              hipStream_t stream) {
    const float* x  = (const float*)d_in[0];
    const float* Wq = (const float*)d_in[1];
    const float* Wk = (const float*)d_in[2];
    const float* Wv = (const float*)d_in[3];
    const float* Wo = (const float*)d_in[4];
    float* out = (float*)d_out;

    float* ws = (float*)d_ws;
    float*  qb  = ws;                                   // 4M f32 (B,S,QH,DH)
    float*  kb  = qb + (size_t)cM * cQH * cDH;          // 1M f32
    float*  vb  = kb + (size_t)cM * cKVH * cDH;         // 1M f32
    ushort* xh  = (ushort*)(vb + (size_t)cM * cKVH * cDH);  // 4M bf16
    ushort* Wqh = xh  + (size_t)cM * cD;                // 1M bf16
    ushort* Wkh = Wqh + (size_t)cQH * cDH * cD;         // 256K bf16
    ushort* Wvh = Wkh + (size_t)cKVH * cDH * cD;        // 256K bf16
    ushort* Woh = Wvh + (size_t)cKVH * cDH * cD;        // 1M bf16
    ushort* abh = Woh + (size_t)cD * cQH * cDH;         // 4M bf16
    ushort* kff = abh + (size_t)cM * cQH * cDH;         // 1M f16 (roped k)
    ushort* qff = kff + (size_t)cM * cKVH * cDH;        // 4M f16 (roped q/8)
    // f16 v aliased into kb's fp32 slot (kb is dead after its rope_cast)
    ushort* vff = (ushort*)kb;                          // 1M f16

    dim3 blk(256);

    // casts to bf16 (GEMM inputs)
    {
        const int nx  = cM * cD;
        const int nwq = cQH * cDH * cD;
        const int nwk = cKVH * cDH * cD;
        const int nwo = cD * cQH * cDH;
        cast_f32_bf16<<<(nx / 4 + 255) / 256, blk, 0, stream>>>(x, xh, nx);
        cast_f32_bf16<<<(nwq / 4 + 255) / 256, blk, 0, stream>>>(Wq, Wqh, nwq);
        cast_f32_bf16<<<(nwk / 4 + 255) / 256, blk, 0, stream>>>(Wk, Wkh, nwk);
        cast_f32_bf16<<<(nwk / 4 + 255) / 256, blk, 0, stream>>>(Wv, Wvh, nwk);
        cast_f32_bf16<<<(nwo / 4 + 255) / 256, blk, 0, stream>>>(Wo, Woh, nwo);
    }

    // QKV projections (bf16 MFMA, fp32 out)
    gemm_bf16_bt<<<dim3((cQH * cDH) / 128, cM / 128), blk, 0, stream>>>(xh, Wqh, qb, cM, cQH * cDH, cD);
    gemm_bf16_bt<<<dim3((cKVH * cDH) / 128, cM / 128), blk, 0, stream>>>(xh, Wkh, kb, cM, cKVH * cDH, cD);
    gemm_bf16_bt<<<dim3((cKVH * cDH) / 128, cM / 128), blk, 0, stream>>>(xh, Wvh, vb, cM, cKVH * cDH, cD);

    // Fused RoPE + cast to f16 (q pre-scaled by 1/sqrt(DH)); v cast to f16.
    // NOTE: v cast runs after k's rope_cast so reusing kb's space is safe
    // (same stream => ordered).
    {
        int totq = cM * cQH * 32;
        int totk = cM * cKVH * 32;
        rope_cast_f16<<<(totq + 255) / 256, blk, 0, stream>>>(qb, qff, cQH, totq, 0.125f);
        rope_cast_f16<<<(totk + 255) / 256, blk, 0, stream>>>(kb, kff, cKVH, totk, 1.0f);
        const int nv = cM * cKVH * cDH;
        cast_f32_f16<<<(nv / 4 + 255) / 256, blk, 0, stream>>>(vb, vff, nv);
    }

    // Attention: MFMA tile kernel, 152KB dynamic LDS (needs >64KB opt-in)
    constexpr size_t aSMEM =
        (size_t)cTI * cLDW * sizeof(float) + 2ull * 8 * cLSZ * 4;  // 155,776 B
    static bool s_attr_done = false;
    if (!s_attr_done) {
        hipFuncSetAttribute(reinterpret_cast<const void*>(attn_tile_kernel),
                            hipFuncAttributeMaxDynamicSharedMemorySize,
                            (int)aSMEM);
        s_attr_done = true;
    }
    attn_tile_kernel<<<dim3((cB * cQH) * (cS / cTI)), dim3(512), aSMEM, stream>>>(
        qff, kff, vff, abh);

    // Output projection (bf16 MFMA, fp32 out)
    gemm_bf16_bt<<<dim3(cD / 128, cM / 128), blk, 0, stream>>>(abh, Woh, out, cM, cD, cD);
}

// Round 2
// 996.087 us; speedup vs baseline: 1.2223x; 1.2223x over previous
//
#include <hip/hip_runtime.h>
#include <hip/hip_bf16.h>
#include <hip/hip_fp16.h>
#include <math.h>

// Problem constants
constexpr int cB   = 2;
constexpr int cS   = 2048;
constexpr int cD   = 1024;
constexpr int cQH  = 16;
constexpr int cKVH = 4;
constexpr int cDH  = 64;
constexpr int cTOPK = 128;
constexpr int cM   = cB * cS;          // 4096 rows for all GEMMs
constexpr int cNB  = cS / 64;          // 32 j-blocks of 64
constexpr int cLSZ = 384;              // kept-list capacity (128 + tie slack)

// Attention tiling
constexpr int cTI  = 16;               // query rows per workgroup (= 16 waves)
constexpr int cLDW = cS + 2;           // LDS score row stride (pad: 4*cLDW%32=8)

typedef __attribute__((ext_vector_type(8))) short short8;
typedef __attribute__((ext_vector_type(4))) float floatx4;
typedef _Float16 half8 __attribute__((ext_vector_type(8)));

// fp32 -> bf16 round-to-nearest-even (no NaN inputs in this problem)
__device__ inline ushort f2bf(float f) {
    unsigned u = __float_as_uint(f);
    return (ushort)((u + 0x7FFFu + ((u >> 16) & 1u)) >> 16);
}

// ---------------------------------------------------------------------------
// Cast fp32 -> bf16 (raw ushort), n multiple of 4.
// ---------------------------------------------------------------------------
__global__ void cast_f32_bf16(const float* __restrict__ src,
                              ushort* __restrict__ dst, int n) {
    int i4 = (blockIdx.x * blockDim.x + threadIdx.x) * 4;
    if (i4 >= n) return;
    const float4 v = *(const float4*)(src + i4);
    ushort4 r;
    r.x = f2bf(v.x); r.y = f2bf(v.y); r.z = f2bf(v.z); r.w = f2bf(v.w);
    *(ushort4*)(dst + i4) = r;
}

// ---------------------------------------------------------------------------
// Cast fp32 -> f16 (raw ushort), n multiple of 4.
// ---------------------------------------------------------------------------
__global__ void cast_f32_f16(const float* __restrict__ src,
                             ushort* __restrict__ dst, int n) {
    int i4 = (blockIdx.x * blockDim.x + threadIdx.x) * 4;
    if (i4 >= n) return;
    const float4 v = *(const float4*)(src + i4);
    ushort4 r;
    r.x = __builtin_bit_cast(ushort, (_Float16)v.x);
    r.y = __builtin_bit_cast(ushort, (_Float16)v.y);
    r.z = __builtin_bit_cast(ushort, (_Float16)v.z);
    r.w = __builtin_bit_cast(ushort, (_Float16)v.w);
    *(ushort4*)(dst + i4) = r;
}

// ---------------------------------------------------------------------------
// MFMA bf16 GEMM: C[m][n] = sum_k A[m][k] * W[n][k]  (A @ W^T).
// 128x128 block tile, BK=32, 256 threads = 4 waves (2x2 of 64x64).
// ---------------------------------------------------------------------------
__global__ __launch_bounds__(256) void gemm_bf16_bt(
        const ushort* __restrict__ A, const ushort* __restrict__ W,
        float* __restrict__ C, int M, int N, int K) {
    __shared__ short As[4][128][8];
    __shared__ short Bs[4][128][8];

    const int tid  = threadIdx.x;
    const int lane = tid & 63;
    const int w    = tid >> 6;          // 0..3
    const int wm   = (w & 1) * 64;
    const int wn   = (w >> 1) * 64;
    const int m0   = blockIdx.y * 128;
    const int n0   = blockIdx.x * 128;

    const int quad = lane >> 4;
    const int l16  = lane & 15;

    floatx4 acc[4][4];
    #pragma unroll
    for (int mi = 0; mi < 4; ++mi)
        #pragma unroll
        for (int ni = 0; ni < 4; ++ni)
            acc[mi][ni] = (floatx4){0.f, 0.f, 0.f, 0.f};

    const int sr = tid >> 1;            // staging row 0..127
    const int sh = (tid & 1) * 2;       // k-chunk pair 0 or 2

    for (int k0 = 0; k0 < K; k0 += 32) {
        const ushort* sa = A + (size_t)(m0 + sr) * K + k0 + sh * 8;
        const short8 a0 = *(const short8*)sa;
        const short8 a1 = *(const short8*)(sa + 8);
        const ushort* sw = W + (size_t)(n0 + sr) * K + k0 + sh * 8;
        const short8 b0 = *(const short8*)sw;
        const short8 b1 = *(const short8*)(sw + 8);
        *(short8*)&As[sh][sr][0]     = a0;
        *(short8*)&As[sh + 1][sr][0] = a1;
        *(short8*)&Bs[sh][sr][0]     = b0;
        *(short8*)&Bs[sh + 1][sr][0] = b1;
        __syncthreads();

        short8 af[4], bf[4];
        #pragma unroll
        for (int mi = 0; mi < 4; ++mi)
            af[mi] = *(const short8*)&As[quad][wm + mi * 16 + l16][0];
        #pragma unroll
        for (int ni = 0; ni < 4; ++ni)
            bf[ni] = *(const short8*)&Bs[quad][wn + ni * 16 + l16][0];
        #pragma unroll
        for (int mi = 0; mi < 4; ++mi)
            #pragma unroll
            for (int ni = 0; ni < 4; ++ni)
                acc[mi][ni] = __builtin_amdgcn_mfma_f32_16x16x32_bf16(
                    af[mi], bf[ni], acc[mi][ni], 0, 0, 0);
        __syncthreads();
    }

    // D layout: col = lane&15, row = quad*4 + reg
    #pragma unroll
    for (int mi = 0; mi < 4; ++mi)
        #pragma unroll
        for (int ni = 0; ni < 4; ++ni)
            #pragma unroll
            for (int r = 0; r < 4; ++r) {
                const int row = m0 + wm + mi * 16 + quad * 4 + r;
                const int col = n0 + wn + ni * 16 + l16;
                C[(size_t)row * N + col] = acc[mi][ni][r];
            }
}

// ---------------------------------------------------------------------------
// RoPE + scale + cast to f16, out of place.
// src layout (B*S, H, DH) fp32; dst same layout, f16 bits in ushort.
// ---------------------------------------------------------------------------
__global__ void rope_cast_f16(const float* __restrict__ src,
                              ushort* __restrict__ dst, int H, int total,
                              float scale) {
    int idx = blockIdx.x * blockDim.x + threadIdx.x;
    if (idx >= total) return;
    const int d   = idx & 31;
    const int h   = (idx >> 5) % H;
    const int row = idx / (32 * H);
    const int s   = row % cS;
    const float inv_freq = powf(10000.0f, -(float)d / 32.0f);
    const float ang = (float)s * inv_freq;
    const float c  = cosf(ang);
    const float si = sinf(ang);
    const float* p = src + (size_t)row * H * cDH + (size_t)h * cDH;
    const float x1 = p[d];
    const float x2 = p[d + 32];
    const float r1 = (x1 * c - x2 * si) * scale;
    const float r2 = (x2 * c + x1 * si) * scale;
    ushort* o = dst + (size_t)row * H * cDH + (size_t)h * cDH;
    o[d]      = __builtin_bit_cast(ushort, (_Float16)r1);
    o[d + 32] = __builtin_bit_cast(ushort, (_Float16)r2);
}

// ---------------------------------------------------------------------------
// Order-preserving float <-> uint bit maps (no NaNs here).
// ---------------------------------------------------------------------------
__device__ inline unsigned fmap(float f) {
    unsigned u = __float_as_uint(f);
    return (u & 0x80000000u) ? ~u : (u | 0x80000000u);
}
__device__ inline float funmap(unsigned u) {
    unsigned v = (u & 0x80000000u) ? (u & 0x7FFFFFFFu) : ~u;
    return __uint_as_float(v);
}

// ---------------------------------------------------------------------------
// MFMA tile attention with exact top-k threshold.  (R13 -> R14 changes)
//
// Workgroup = 1024 threads = 16 waves, owns cTI=16 query rows of one (b,h).
// R13 post-mortem: phase 2 (bisection chain) is latency-bound; 8 waves/CU at
// 152KB LDS starved it (23% occupancy, VALUBusy 28%).  R14:
//  - 16 waves, ONE row per wave in phase 2 (halves block critical path).
//  - LDS cut to 131KB: kl/jl lists ALIAS the score buffer (keys are loaded
//    into registers first, then __syncthreads, then lists may clobber Sc).
//  - fmap + causal mask folded into phase 1's MFMA epilogue: Sc holds
//    ready-to-use uint keys (masked = 0), phase-2 reload is bare ds_read.
// Phase 1: scores via mfma_f32_16x16x32_f16 (16 q-rows x 16 keys per block,
//   K=64 via 2 chained MFMAs). Fragment layout taken from gemm_bf16_bt above
//   (A/B: row = lane&15, k = quad*8+e; D: row = quad*4+r, col = lane&15).
// Phase 2 per wave: proven exact path, unchanged:
//  - key[32] 1D fully unrolled (R5/R6: 2D/runtime-indexed -> scratch spill).
//  - no cross-half (>=32) shuffles on the critical chain (R10).
//  - permuted key ownership (R11): selection is permutation-invariant.
//  - 8 independent PV accumulator chains.
// Big-it tiles dispatched first (descending it) to avoid a straggler tail.
// ---------------------------------------------------------------------------
__global__ __launch_bounds__(1024) void attn_tile_kernel(
        const ushort* __restrict__ qf, const ushort* __restrict__ kf,
        const ushort* __restrict__ vf, ushort* __restrict__ out) {
    extern __shared__ char smem[];
    unsigned* ScU = (unsigned*)smem;               // [cTI][cLDW] uint keys
    unsigned* klA = (unsigned*)smem;               // aliases Sc rows 0..2
    int*      jlA = (int*)(klA + cTI * cLSZ);      // aliases Sc rows 3..5

    const int lane = threadIdx.x & 63;
    const int wv   = __builtin_amdgcn_readfirstlane(threadIdx.x >> 6); // 0..15

    // grid: 32 * 128 blocks; it descending so the biggest tiles start first
    const int x  = blockIdx.x;
    const int it = (cS / cTI - 1) - (x >> 5);   // 127..0
    const int bh = x & 31;
    const int h  = bh & 15;
    const int b  = bh >> 4;
    const int kvh = h >> 2;                     // h / (QH/KVH)
    const int i0  = it * cTI;
    const int nk16 = it + 1;                    // 16-key blocks to compute

    const size_t bS = (size_t)b * cS;
    const int l16   = lane & 15;
    const int quad  = lane >> 4;

    // ---- Phase 1: scores via MFMA, scattered across 16 waves --------------
    // A-frags: q rows i0 + l16, dims quad*8..quad*8+7 and +32 (f16, pre-scaled)
    const ushort* qp = qf + ((bS + i0 + l16) * cQH + h) * cDH + quad * 8;
    const uint4 a0 = *(const uint4*)qp;
    const uint4 a1 = *(const uint4*)(qp + 32);
    const half8 a0h = __builtin_bit_cast(half8, a0);
    const half8 a1h = __builtin_bit_cast(half8, a1);

    int jb16 = wv;
    if (jb16 < nk16) {
        const ushort* kp0 = kf + ((bS + (jb16 << 4) + l16) * cKVH + kvh) * cDH + quad * 8;
        uint4 pb0 = *(const uint4*)kp0;
        uint4 pb1 = *(const uint4*)(kp0 + 32);
        while (jb16 < nk16) {
            const uint4 b0 = pb0;
            const uint4 b1 = pb1;
            const int jn = jb16 + 16;
            if (jn < nk16) {   // software pipeline: prefetch next key block
                const ushort* kp = kf + ((bS + (jn << 4) + l16) * cKVH + kvh) * cDH + quad * 8;
                pb0 = *(const uint4*)kp;
                pb1 = *(const uint4*)(kp + 32);
            }
            floatx4 acc = (floatx4){0.f, 0.f, 0.f, 0.f};
            acc = __builtin_amdgcn_mfma_f32_16x16x32_f16(
                a0h, __builtin_bit_cast(half8, b0), acc, 0, 0, 0);
            acc = __builtin_amdgcn_mfma_f32_16x16x32_f16(
                a1h, __builtin_bit_cast(half8, b1), acc, 0, 0, 0);
            // D: row = quad*4 + r (q row in tile), col = l16 (key in block).
            // Fold fmap + causal mask here: Sc holds final uint keys.
            const int colbase = (jb16 << 4) + l16;     // key index j
            #pragma unroll
            for (int r2 = 0; r2 < 4; ++r2) {
                const int qrow = quad * 4 + r2;
                const unsigned kv =
                    (colbase <= i0 + qrow) ? fmap(acc[r2]) : 0u;
                ScU[qrow * cLDW + colbase] = kv;
            }
            jb16 = jn;
        }
    }
    __syncthreads();

    // ---- Phase 2: per-row exact top-k + softmax + PV (1 row per wave) -----
    const int jperm = ((lane & 3) << 4) + (lane >> 2);   // permuted ownership
    unsigned* kl = klA + wv * cLSZ;
    int*      jl = jlA + wv * cLSZ;
    const int vbase0 = (int)(((unsigned)bS * cKVH + kvh) * cDH);

    const int i  = i0 + wv;              // this wave's query row
    const int nb = (i >> 6) + 1;

    // reload this row's keys (2-way LDS reads: conflict-free).  Keys beyond
    // the causal frontier were stored as 0 by phase 1; only the last block
    // can read lanes past the written region, masked by j<=i below.
    unsigned key[cNB];
    #pragma unroll
    for (int jb = 0; jb < cNB; ++jb) {
        unsigned kreg = 0u;
        if (jb < nb) {
            const int j = (jb << 6) + jperm;
            kreg = ScU[wv * cLDW + j];
            kreg = (j <= i) ? kreg : 0u;   // guards unwritten LDS in last block
        }
        key[jb] = kreg;
    }
    __syncthreads();   // all waves hold keys in regs; lists may clobber Sc

    // row max + min over valid keys (valid keys are never 0)
    unsigned um = 0u, un = 0xFFFFFFFFu;
    #pragma unroll
    for (int jb = 0; jb < cNB; ++jb) {
        if (jb >= nb) break;
        const unsigned kk = key[jb];
        um = max(um, kk);
        un = min(un, kk ? kk : 0xFFFFFFFFu);
    }
    #pragma unroll
    for (int off = 32; off >= 1; off >>= 1) {
        um = max(um, (unsigned)__shfl_xor((int)um, off));
        un = min(un, (unsigned)__shfl_xor((int)un, off));
    }
    const float mrow = funmap(um);

    // exact 128th-largest key via bisection in [un, um]
    unsigned lo = un, hi = um;
    while (lo < hi) {
        const unsigned d   = hi - lo;
        const unsigned mid = lo + (d >> 1) + (d & 1u);
        int cnt2 = 0;
        #pragma unroll
        for (int jb = 0; jb < cNB; ++jb) {
            if (jb >= nb) break;
            cnt2 += __popcll(__ballot(key[jb] >= mid));
        }
        if (cnt2 >= cTOPK) lo = mid; else hi = mid - 1u;
    }
    const unsigned ustar = lo;

    // ballot-prefix compaction of kept (j, key) into LDS
    const unsigned long long mlt = (1ull << lane) - 1ull;
    int base = 0;
    #pragma unroll
    for (int jb = 0; jb < cNB; ++jb) {
        if (jb >= nb) break;
        const int j = (jb << 6) + jperm;
        const bool keep = (j <= i) && (key[jb] >= ustar);
        const unsigned long long mk = __ballot(keep);
        const int pos = base + __popcll(mk & mlt);
        if (keep && pos < cLSZ) {
            kl[pos] = key[jb];
            jl[pos] = vbase0 + j * (cKVH * cDH);   // v element offset
        }
        base += __popcll(mk);
    }
    const int cnt = min(base, cLSZ);

    // weights + Z
    float zp = 0.f;
    for (int t = lane; t < cnt; t += 64) {
        const float s  = funmap(kl[t]);
        const float wt = __expf(s - mrow);
        ((float*)kl)[t] = wt;
        zp += wt;
    }
    #pragma unroll
    for (int off = 32; off >= 1; off >>= 1) zp += __shfl_xor(zp, off);
    const float invZ = 1.0f / zp;

    // PV: lane = d, f16 v, 8 independent accumulator chains
    float ac0 = 0.f, ac1 = 0.f, ac2 = 0.f, ac3 = 0.f;
    float ac4 = 0.f, ac5 = 0.f, ac6 = 0.f, ac7 = 0.f;
    int t = 0;
    for (; t + 7 < cnt; t += 8) {
        const float wt0 = ((float*)kl)[t];
        const float wt1 = ((float*)kl)[t + 1];
        const float wt2 = ((float*)kl)[t + 2];
        const float wt3 = ((float*)kl)[t + 3];
        const float wt4 = ((float*)kl)[t + 4];
        const float wt5 = ((float*)kl)[t + 5];
        const float wt6 = ((float*)kl)[t + 6];
        const float wt7 = ((float*)kl)[t + 7];
        const int vo0 = jl[t];
        const int vo1 = jl[t + 1];
        const int vo2 = jl[t + 2];
        const int vo3 = jl[t + 3];
        const int vo4 = jl[t + 4];
        const int vo5 = jl[t + 5];
        const int vo6 = jl[t + 6];
        const int vo7 = jl[t + 7];
        ac0 += wt0 * (float)__builtin_bit_cast(_Float16, vf[vo0 + lane]);
        ac1 += wt1 * (float)__builtin_bit_cast(_Float16, vf[vo1 + lane]);
        ac2 += wt2 * (float)__builtin_bit_cast(_Float16, vf[vo2 + lane]);
        ac3 += wt3 * (float)__builtin_bit_cast(_Float16, vf[vo3 + lane]);
        ac4 += wt4 * (float)__builtin_bit_cast(_Float16, vf[vo4 + lane]);
        ac5 += wt5 * (float)__builtin_bit_cast(_Float16, vf[vo5 + lane]);
        ac6 += wt6 * (float)__builtin_bit_cast(_Float16, vf[vo6 + lane]);
        ac7 += wt7 * (float)__builtin_bit_cast(_Float16, vf[vo7 + lane]);
    }
    for (; t < cnt; ++t) {
        const float wt = ((float*)kl)[t];
        const int   vo = jl[t];
        ac0 += wt * (float)__builtin_bit_cast(_Float16, vf[vo + lane]);
    }
    const float acc = ((ac0 + ac1) + (ac2 + ac3)) + ((ac4 + ac5) + (ac6 + ac7));
    out[((bS + i) * cQH + h) * cDH + lane] = f2bf(acc * invZ);
}

// ---------------------------------------------------------------------------
// Launch
// ---------------------------------------------------------------------------
extern "C" void kernel_launch(void* const* d_in, const int* in_sizes, int n_in,
                              void* d_out, int out_size, void* d_ws, size_t ws_size,
                              hipStream_t stream) {
    const float* x  = (const float*)d_in[0];
    const float* Wq = (const float*)d_in[1];
    const float* Wk = (const float*)d_in[2];
    const float* Wv = (const float*)d_in[3];
    const float* Wo = (const float*)d_in[4];
    float* out = (float*)d_out;

    float* ws = (float*)d_ws;
    float*  qb  = ws;                                   // 4M f32 (B,S,QH,DH)
    float*  kb  = qb + (size_t)cM * cQH * cDH;          // 1M f32
    float*  vb  = kb + (size_t)cM * cKVH * cDH;         // 1M f32
    ushort* xh  = (ushort*)(vb + (size_t)cM * cKVH * cDH);  // 4M bf16
    ushort* Wqh = xh  + (size_t)cM * cD;                // 1M bf16
    ushort* Wkh = Wqh + (size_t)cQH * cDH * cD;         // 256K bf16
    ushort* Wvh = Wkh + (size_t)cKVH * cDH * cD;        // 256K bf16
    ushort* Woh = Wvh + (size_t)cKVH * cDH * cD;        // 1M bf16
    ushort* abh = Woh + (size_t)cD * cQH * cDH;         // 4M bf16
    ushort* kff = abh + (size_t)cM * cQH * cDH;         // 1M f16 (roped k)
    ushort* qff = kff + (size_t)cM * cKVH * cDH;        // 4M f16 (roped q/8)
    // f16 v aliased into kb's fp32 slot (kb is dead after its rope_cast)
    ushort* vff = (ushort*)kb;                          // 1M f16

    dim3 blk(256);

    // casts to bf16 (GEMM inputs)
    {
        const int nx  = cM * cD;
        const int nwq = cQH * cDH * cD;
        const int nwk = cKVH * cDH * cD;
        const int nwo = cD * cQH * cDH;
        cast_f32_bf16<<<(nx / 4 + 255) / 256, blk, 0, stream>>>(x, xh, nx);
        cast_f32_bf16<<<(nwq / 4 + 255) / 256, blk, 0, stream>>>(Wq, Wqh, nwq);
        cast_f32_bf16<<<(nwk / 4 + 255) / 256, blk, 0, stream>>>(Wk, Wkh, nwk);
        cast_f32_bf16<<<(nwk / 4 + 255) / 256, blk, 0, stream>>>(Wv, Wvh, nwk);
        cast_f32_bf16<<<(nwo / 4 + 255) / 256, blk, 0, stream>>>(Wo, Woh, nwo);
    }

    // QKV projections (bf16 MFMA, fp32 out)
    gemm_bf16_bt<<<dim3((cQH * cDH) / 128, cM / 128), blk, 0, stream>>>(xh, Wqh, qb, cM, cQH * cDH, cD);
    gemm_bf16_bt<<<dim3((cKVH * cDH) / 128, cM / 128), blk, 0, stream>>>(xh, Wkh, kb, cM, cKVH * cDH, cD);
    gemm_bf16_bt<<<dim3((cKVH * cDH) / 128, cM / 128), blk, 0, stream>>>(xh, Wvh, vb, cM, cKVH * cDH, cD);

    // Fused RoPE + cast to f16 (q pre-scaled by 1/sqrt(DH)); v cast to f16.
    // NOTE: v cast runs after k's rope_cast so reusing kb's space is safe
    // (same stream => ordered).
    {
        int totq = cM * cQH * 32;
        int totk = cM * cKVH * 32;
        rope_cast_f16<<<(totq + 255) / 256, blk, 0, stream>>>(qb, qff, cQH, totq, 0.125f);
        rope_cast_f16<<<(totk + 255) / 256, blk, 0, stream>>>(kb, kff, cKVH, totk, 1.0f);
        const int nv = cM * cKVH * cDH;
        cast_f32_f16<<<(nv / 4 + 255) / 256, blk, 0, stream>>>(vb, vff, nv);
    }

    // Attention: MFMA tile kernel, 131KB dynamic LDS (lists alias score buf)
    constexpr size_t aSMEM = (size_t)cTI * cLDW * sizeof(float);  // 131,200 B
    static bool s_attr_done = false;
    if (!s_attr_done) {
        hipFuncSetAttribute(reinterpret_cast<const void*>(attn_tile_kernel),
                            hipFuncAttributeMaxDynamicSharedMemorySize,
                            (int)aSMEM);
        s_attr_done = true;
    }
    attn_tile_kernel<<<dim3((cB * cQH) * (cS / cTI)), dim3(1024), aSMEM, stream>>>(
        qff, kff, vff, abh);

    // Output projection (bf16 MFMA, fp32 out)
    gemm_bf16_bt<<<dim3(cD / 128, cM / 128), blk, 0, stream>>>(abh, Woh, out, cM, cD, cD);
}